// Round 4
// baseline (179.998 us; speedup 1.0000x reference)
//
#include <hip/hip_runtime.h>
#include <hip/hip_cooperative_groups.h>

namespace cg = cooperative_groups;

#define NROWS 2048
#define MCOLS 2048
#define DDIM  64
#define TILE  64
#define NTI   32   // tile-rows
#define NTJ   32   // tile-cols

// ============================================================================
// Shared helpers (used by both coop and fallback paths)
// ============================================================================

// Computes sv[a][b] = s[bi*64 + (t>>4)*4 + a][bj*64 + (t&15)*4 + b]
// via LDS-transposed tiles. s = -sum_d |x-y|. Caller must __syncthreads()
// before re-entering with different (bi,bj) (LDS reuse).
__device__ __forceinline__ void stage_tiles(
    const float* __restrict__ zx, const float* __restrict__ zy,
    int bi, int bj, float (*sX)[TILE], float (*sY)[TILE])
{
  int t = threadIdx.x;
  int r  = t & 63;
  int d0 = (t >> 6) << 2;
  const float* zxp = zx + (size_t)(bi * TILE + r) * DDIM;
  const float* zyp = zy + (size_t)(bj * TILE + r) * DDIM;
#pragma unroll
  for (int q = 0; q < 4; ++q) {
    int d = d0 + 16 * q;
    float4 xv = *(const float4*)(zxp + d);
    float4 yv = *(const float4*)(zyp + d);
    sX[d+0][r]=xv.x; sX[d+1][r]=xv.y; sX[d+2][r]=xv.z; sX[d+3][r]=xv.w;
    sY[d+0][r]=yv.x; sY[d+1][r]=yv.y; sY[d+2][r]=yv.z; sY[d+3][r]=yv.w;
  }
}

__device__ __forceinline__ void compute_sv(
    const float (*sX)[TILE], const float (*sY)[TILE],
    int i0, int j0, float sv[4][4])
{
  float acc[4][4] = {{0.f}};
#pragma unroll 8
  for (int d = 0; d < DDIM; ++d) {
    float4 xv = *(const float4*)&sX[d][i0];
    float4 yv = *(const float4*)&sY[d][j0];
    float xr[4] = {xv.x, xv.y, xv.z, xv.w};
    float yc[4] = {yv.x, yv.y, yv.z, yv.w};
#pragma unroll
    for (int a = 0; a < 4; ++a)
#pragma unroll
      for (int b = 0; b < 4; ++b)
        acc[a][b] += fabsf(xr[a] - yc[b]);
  }
#pragma unroll
  for (int a = 0; a < 4; ++a)
#pragma unroll
    for (int b = 0; b < 4; ++b)
      sv[a][b] = -acc[a][b];
}

// Emits per-tile (max, expsum) partials for rows and cols. Includes one
// __syncthreads (cmw/csw staging).
__device__ __forceinline__ void tile_stats(
    const float sv[4][4], int bi, int bj,
    float* __restrict__ rm_part, float* __restrict__ rs_part,
    float* __restrict__ cm_part, float* __restrict__ cs_part,
    float (*cmw)[TILE], float (*csw)[TILE])
{
  int t = threadIdx.x;
  int lid = t & 63, wv = t >> 6;
  int i0 = (t >> 4) << 2, j0 = (t & 15) << 2;

  // row stats (16 lanes, bits 0..3 cover one tile-row)
  float rm[4], es[4];
#pragma unroll
  for (int a = 0; a < 4; ++a)
    rm[a] = fmaxf(fmaxf(sv[a][0], sv[a][1]), fmaxf(sv[a][2], sv[a][3]));
#pragma unroll
  for (int off = 1; off <= 8; off <<= 1)
#pragma unroll
    for (int a = 0; a < 4; ++a)
      rm[a] = fmaxf(rm[a], __shfl_xor(rm[a], off));
#pragma unroll
  for (int a = 0; a < 4; ++a)
    es[a] = __expf(sv[a][0]-rm[a]) + __expf(sv[a][1]-rm[a])
          + __expf(sv[a][2]-rm[a]) + __expf(sv[a][3]-rm[a]);
#pragma unroll
  for (int off = 1; off <= 8; off <<= 1)
#pragma unroll
    for (int a = 0; a < 4; ++a)
      es[a] += __shfl_xor(es[a], off);
  if ((lid & 15) == 0) {
#pragma unroll
    for (int a = 0; a < 4; ++a) {
      int idx = bj * NROWS + bi * TILE + i0 + a;
      rm_part[idx] = rm[a];
      rs_part[idx] = es[a];
    }
  }

  // col stats (bits 4..5 within wave, then LDS across 4 waves)
  float cm[4], ce[4];
#pragma unroll
  for (int b = 0; b < 4; ++b)
    cm[b] = fmaxf(fmaxf(sv[0][b], sv[1][b]), fmaxf(sv[2][b], sv[3][b]));
#pragma unroll
  for (int off = 16; off <= 32; off <<= 1)
#pragma unroll
    for (int b = 0; b < 4; ++b)
      cm[b] = fmaxf(cm[b], __shfl_xor(cm[b], off));
#pragma unroll
  for (int b = 0; b < 4; ++b)
    ce[b] = __expf(sv[0][b]-cm[b]) + __expf(sv[1][b]-cm[b])
          + __expf(sv[2][b]-cm[b]) + __expf(sv[3][b]-cm[b]);
#pragma unroll
  for (int off = 16; off <= 32; off <<= 1)
#pragma unroll
    for (int b = 0; b < 4; ++b)
      ce[b] += __shfl_xor(ce[b], off);
  if (lid < 16) {
#pragma unroll
    for (int b = 0; b < 4; ++b) {
      cmw[wv][lid * 4 + b] = cm[b];
      csw[wv][lid * 4 + b] = ce[b];
    }
  }
  __syncthreads();
  if (t < TILE) {
    int j = t;
    float M = fmaxf(fmaxf(cmw[0][j], cmw[1][j]), fmaxf(cmw[2][j], cmw[3][j]));
    float S = __expf(cmw[0][j]-M)*csw[0][j] + __expf(cmw[1][j]-M)*csw[1][j]
            + __expf(cmw[2][j]-M)*csw[2][j] + __expf(cmw[3][j]-M)*csw[3][j];
    int idx = bi * MCOLS + bj * TILE + j;
    cm_part[idx] = M;
    cs_part[idx] = S;
  }
}

// ============================================================================
// Cooperative single-kernel path: grid = 512 blocks x 256 threads,
// 2 tiles per block, sv fragments live in registers across grid syncs.
// Needs only 2 blocks/CU co-resident (occupancy allows 4 -> 2x margin).
// ============================================================================
__global__ __launch_bounds__(256, 4) void fused2(
    const float* __restrict__ zx, const float* __restrict__ zy,
    float* __restrict__ rm_part, float* __restrict__ rs_part,
    float* __restrict__ cm_part, float* __restrict__ cs_part,
    float* __restrict__ rowmax, float* __restrict__ rowinv,
    float* __restrict__ colmax, float* __restrict__ colinv,
    float* __restrict__ part, float* __restrict__ out)
{
  __shared__ float sX[DDIM][TILE];
  __shared__ float sY[DDIM][TILE];
  __shared__ float cmw[4][TILE];
  __shared__ float csw[4][TILE];
  __shared__ float red[8];

  cg::grid_group gg = cg::this_grid();

  const int bid = blockIdx.x;
  const int t   = threadIdx.x;
  const int lid = t & 63, wv = t >> 6;
  const int i0  = (t >> 4) << 2;
  const int j0  = (t & 15) << 2;

  float sv[2][4][4];

  // ================= Phase A: distances + tile stats (2 tiles) ==============
#pragma unroll
  for (int u = 0; u < 2; ++u) {
    int tile = (bid << 1) | u;
    int bi = tile >> 5, bj = tile & 31;
    stage_tiles(zx, zy, bi, bj, sX, sY);
    __syncthreads();
    compute_sv(sX, sY, i0, j0, sv[u]);
    tile_stats(sv[u], bi, bj, rm_part, rs_part, cm_part, cs_part, cmw, csw);
    __syncthreads();  // protect sX/sY + cmw/csw before next iteration reuse
  }

  gg.sync();

  // ================= Phase B: reduce 32 partials per row/col ================
  {
    int g = bid * 256 + t;
    if (g < NROWS) {
      int i = g;
      float M = -3.4e38f;
#pragma unroll 8
      for (int tj = 0; tj < NTJ; ++tj) M = fmaxf(M, rm_part[tj * NROWS + i]);
      float S = 0.f;
#pragma unroll 8
      for (int tj = 0; tj < NTJ; ++tj)
        S += __expf(rm_part[tj * NROWS + i] - M) * rs_part[tj * NROWS + i];
      rowmax[i] = M;
      rowinv[i] = 1.f / S;
    } else if (g < NROWS + MCOLS) {
      int j = g - NROWS;
      float M = -3.4e38f;
#pragma unroll 8
      for (int ti = 0; ti < NTI; ++ti) M = fmaxf(M, cm_part[ti * MCOLS + j]);
      float S = 0.f;
#pragma unroll 8
      for (int ti = 0; ti < NTI; ++ti)
        S += __expf(cm_part[ti * MCOLS + j] - M) * cs_part[ti * MCOLS + j];
      colmax[j] = M;
      colinv[j] = 1.f / S;
    }
  }

  gg.sync();

  // ============ Phase C: combine straight from registers (sv live) ==========
  {
    float pn = 0.f, pd = 0.f;
#pragma unroll
    for (int u = 0; u < 2; ++u) {
      int tile = (bid << 1) | u;
      int bi = tile >> 5, bj = tile & 31;
      float rm[4], rv[4], cm[4], cv[4];
#pragma unroll
      for (int a = 0; a < 4; ++a) {
        rm[a] = rowmax[bi * TILE + i0 + a];
        rv[a] = rowinv[bi * TILE + i0 + a];
      }
#pragma unroll
      for (int b = 0; b < 4; ++b) {
        cm[b] = colmax[bj * TILE + j0 + b];
        cv[b] = colinv[bj * TILE + j0 + b];
      }
#pragma unroll
      for (int a = 0; a < 4; ++a)
#pragma unroll
        for (int b = 0; b < 4; ++b) {
          float av = __expf(sv[u][a][b] - rm[a]) * rv[a];
          float bv = __expf(sv[u][a][b] - cm[b]) * cv[b];
          float w  = av + bv - av * bv;
          pn += w * sv[u][a][b];
          pd += w;
        }
    }
#pragma unroll
    for (int off = 1; off <= 32; off <<= 1) {
      pn += __shfl_xor(pn, off);
      pd += __shfl_xor(pd, off);
    }
    if (lid == 0) { red[wv * 2] = pn; red[wv * 2 + 1] = pd; }
    __syncthreads();
    if (t == 0) {
      part[bid * 2 + 0] = red[0] + red[2] + red[4] + red[6];
      part[bid * 2 + 1] = red[1] + red[3] + red[5] + red[7];
    }
  }

  gg.sync();

  // ================= Phase D: block 0 reduces 512 partials ==================
  if (bid == 0) {
    float pn = 0.f, pd = 0.f;
    for (int k = t; k < 512; k += 256) {
      pn += part[k * 2 + 0];
      pd += part[k * 2 + 1];
    }
#pragma unroll
    for (int off = 1; off <= 32; off <<= 1) {
      pn += __shfl_xor(pn, off);
      pd += __shfl_xor(pd, off);
    }
    if (lid == 0) { red[wv * 2] = pn; red[wv * 2 + 1] = pd; }
    __syncthreads();
    if (t == 0) {
      float n = red[0] + red[2] + red[4] + red[6];
      float d = red[1] + red[3] + red[5] + red[7];
      out[0] = n / d;
    }
  }
}

// ============================================================================
// Fallback path: the R2 4-kernel pipeline (known good, 46.7 us)
// ============================================================================

__device__ __forceinline__ void load_tile_s(
    const float* __restrict__ s_in, int bi, int bj, float sv[4][4])
{
  int t = threadIdx.x;
  int i0 = (t >> 4) << 2;
  int j0 = (t & 15) << 2;
  const float* base = s_in + (size_t)(bi * TILE + i0) * MCOLS + bj * TILE + j0;
#pragma unroll
  for (int a = 0; a < 4; ++a) {
    float4 v = *(const float4*)(base + (size_t)a * MCOLS);
    sv[a][0] = v.x; sv[a][1] = v.y; sv[a][2] = v.z; sv[a][3] = v.w;
  }
}

template<bool STORE>
__global__ __launch_bounds__(256) void k1_stats(
    const float* __restrict__ zx, const float* __restrict__ zy,
    float* __restrict__ s_out,
    float* __restrict__ rm_part, float* __restrict__ rs_part,
    float* __restrict__ cm_part, float* __restrict__ cs_part)
{
  __shared__ float sX[DDIM][TILE];
  __shared__ float sY[DDIM][TILE];
  __shared__ float cmw[4][TILE];
  __shared__ float csw[4][TILE];
  int bi = blockIdx.y, bj = blockIdx.x;
  int t  = threadIdx.x;
  int i0 = (t >> 4) << 2, j0 = (t & 15) << 2;
  float sv[4][4];
  stage_tiles(zx, zy, bi, bj, sX, sY);
  __syncthreads();
  compute_sv(sX, sY, i0, j0, sv);
  if (STORE) {
#pragma unroll
    for (int a = 0; a < 4; ++a) {
      float4 v = make_float4(sv[a][0], sv[a][1], sv[a][2], sv[a][3]);
      *(float4*)(s_out + (size_t)(bi * TILE + i0 + a) * MCOLS + bj * TILE + j0) = v;
    }
  }
  tile_stats(sv, bi, bj, rm_part, rs_part, cm_part, cs_part, cmw, csw);
}

__global__ __launch_bounds__(256) void kr_reduce(
    const float* __restrict__ rm_part, const float* __restrict__ rs_part,
    const float* __restrict__ cm_part, const float* __restrict__ cs_part,
    float* __restrict__ rowmax, float* __restrict__ rowinv,
    float* __restrict__ colmax, float* __restrict__ colinv)
{
  int g = blockIdx.x * 256 + threadIdx.x;
  if (g < NROWS) {
    int i = g;
    float M = -3.4e38f;
#pragma unroll 8
    for (int tj = 0; tj < NTJ; ++tj) M = fmaxf(M, rm_part[tj * NROWS + i]);
    float S = 0.f;
#pragma unroll 8
    for (int tj = 0; tj < NTJ; ++tj)
      S += __expf(rm_part[tj * NROWS + i] - M) * rs_part[tj * NROWS + i];
    rowmax[i] = M;
    rowinv[i] = 1.f / S;
  } else if (g < NROWS + MCOLS) {
    int j = g - NROWS;
    float M = -3.4e38f;
#pragma unroll 8
    for (int ti = 0; ti < NTI; ++ti) M = fmaxf(M, cm_part[ti * MCOLS + j]);
    float S = 0.f;
#pragma unroll 8
    for (int ti = 0; ti < NTI; ++ti)
      S += __expf(cm_part[ti * MCOLS + j] - M) * cs_part[ti * MCOLS + j];
    colmax[j] = M;
    colinv[j] = 1.f / S;
  }
}

template<bool STORE>
__global__ __launch_bounds__(256) void k3_final(
    const float* __restrict__ zx, const float* __restrict__ zy,
    const float* __restrict__ s_in,
    const float* __restrict__ rowmax, const float* __restrict__ rowinv,
    const float* __restrict__ colmax, const float* __restrict__ colinv,
    float* __restrict__ part)
{
  int bi = blockIdx.y, bj = blockIdx.x;
  int t  = threadIdx.x;
  int i0 = (t >> 4) << 2, j0 = (t & 15) << 2;
  float sv[4][4];
  if constexpr (STORE) {
    load_tile_s(s_in, bi, bj, sv);
  } else {
    __shared__ float sX[DDIM][TILE];
    __shared__ float sY[DDIM][TILE];
    stage_tiles(zx, zy, bi, bj, sX, sY);
    __syncthreads();
    compute_sv(sX, sY, i0, j0, sv);
  }
  float rm[4], rv[4], cm[4], cv[4];
#pragma unroll
  for (int a = 0; a < 4; ++a) {
    rm[a] = rowmax[bi * TILE + i0 + a];
    rv[a] = rowinv[bi * TILE + i0 + a];
  }
#pragma unroll
  for (int b = 0; b < 4; ++b) {
    cm[b] = colmax[bj * TILE + j0 + b];
    cv[b] = colinv[bj * TILE + j0 + b];
  }
  float pn = 0.f, pd = 0.f;
#pragma unroll
  for (int a = 0; a < 4; ++a)
#pragma unroll
    for (int b = 0; b < 4; ++b) {
      float av = __expf(sv[a][b] - rm[a]) * rv[a];
      float bv = __expf(sv[a][b] - cm[b]) * cv[b];
      float w  = av + bv - av * bv;
      pn += w * sv[a][b];
      pd += w;
    }
#pragma unroll
  for (int off = 1; off <= 32; off <<= 1) {
    pn += __shfl_xor(pn, off);
    pd += __shfl_xor(pd, off);
  }
  if ((t & 63) == 0) {
    int w = (bi * NTJ + bj) * 4 + (t >> 6);
    part[w * 2 + 0] = pn;
    part[w * 2 + 1] = pd;
  }
}

__global__ __launch_bounds__(256) void k4_out(
    const float* __restrict__ part, int n, float* __restrict__ out)
{
  int t = threadIdx.x;
  float pn = 0.f, pd = 0.f;
  for (int k = t; k < n; k += 256) {
    pn += part[k * 2 + 0];
    pd += part[k * 2 + 1];
  }
#pragma unroll
  for (int off = 1; off <= 32; off <<= 1) {
    pn += __shfl_xor(pn, off);
    pd += __shfl_xor(pd, off);
  }
  __shared__ float red[8];
  if ((t & 63) == 0) { red[(t >> 6) * 2] = pn; red[(t >> 6) * 2 + 1] = pd; }
  __syncthreads();
  if (t == 0) {
    float n2 = red[0] + red[2] + red[4] + red[6];
    float d2 = red[1] + red[3] + red[5] + red[7];
    out[0] = n2 / d2;
  }
}

extern "C" void kernel_launch(void* const* d_in, const int* in_sizes, int n_in,
                              void* d_out, int out_size, void* d_ws, size_t ws_size,
                              hipStream_t stream)
{
  const float* zx = (const float*)d_in[0];
  const float* zy = (const float*)d_in[1];
  float* out = (float*)d_out;

  char* ws = (char*)d_ws;
  float* rowmax  = (float*)(ws + 0);
  float* rowinv  = (float*)(ws + (8  << 10));
  float* colmax  = (float*)(ws + (16 << 10));
  float* colinv  = (float*)(ws + (24 << 10));
  float* part    = (float*)(ws + (32 << 10));   // up to 4096*2 f32
  float* rm_part = (float*)(ws + (64  << 10));  // 32*2048 f32 = 256 KB each
  float* rs_part = (float*)(ws + (320 << 10));
  float* cm_part = (float*)(ws + (576 << 10));
  float* cs_part = (float*)(ws + (832 << 10));
  float* s_buf   = (float*)(ws + (1088 << 10)); // 16 MiB (fallback only)

  void* args[] = {
    (void*)&zx, (void*)&zy,
    (void*)&rm_part, (void*)&rs_part, (void*)&cm_part, (void*)&cs_part,
    (void*)&rowmax, (void*)&rowinv, (void*)&colmax, (void*)&colinv,
    (void*)&part, (void*)&out
  };
  hipError_t err = hipLaunchCooperativeKernel(
      (void*)fused2, dim3(512), dim3(256), args, 0, stream);

  if (err != hipSuccess) {
    // ---- fallback: known-good 4-kernel pipeline ----
    dim3 grid(NTJ, NTI), block(256);
    const size_t NEED = (size_t)(1088 << 10) + (size_t)NROWS * MCOLS * sizeof(float);
    if (ws_size >= NEED) {
      k1_stats<true ><<<grid, block, 0, stream>>>(zx, zy, s_buf, rm_part, rs_part, cm_part, cs_part);
      kr_reduce<<<dim3(16), block, 0, stream>>>(rm_part, rs_part, cm_part, cs_part,
                                                rowmax, rowinv, colmax, colinv);
      k3_final<true ><<<grid, block, 0, stream>>>(zx, zy, s_buf, rowmax, rowinv, colmax, colinv, part);
    } else {
      k1_stats<false><<<grid, block, 0, stream>>>(zx, zy, s_buf, rm_part, rs_part, cm_part, cs_part);
      kr_reduce<<<dim3(16), block, 0, stream>>>(rm_part, rs_part, cm_part, cs_part,
                                                rowmax, rowinv, colmax, colinv);
      k3_final<false><<<grid, block, 0, stream>>>(zx, zy, s_buf, rowmax, rowinv, colmax, colinv, part);
    }
    k4_out<<<dim3(1), block, 0, stream>>>(part, NTI * NTJ * 4, out);
  }
}

// Round 5
// 101.429 us; speedup vs baseline: 1.7746x; 1.7746x over previous
//
#include <hip/hip_runtime.h>
#include <hip/hip_cooperative_groups.h>

#define NROWS 2048
#define MCOLS 2048
#define DDIM  64
#define TILE  64
#define NTI   32   // tile-rows
#define NTJ   32   // tile-cols
#define NBLK  512  // coop grid: 2 tiles per block

// ============================================================================
// Shared helpers
// ============================================================================
__device__ __forceinline__ void stage_tiles(
    const float* __restrict__ zx, const float* __restrict__ zy,
    int bi, int bj, float (*sX)[TILE], float (*sY)[TILE])
{
  int t = threadIdx.x;
  int r  = t & 63;
  int d0 = (t >> 6) << 2;
  const float* zxp = zx + (size_t)(bi * TILE + r) * DDIM;
  const float* zyp = zy + (size_t)(bj * TILE + r) * DDIM;
#pragma unroll
  for (int q = 0; q < 4; ++q) {
    int d = d0 + 16 * q;
    float4 xv = *(const float4*)(zxp + d);
    float4 yv = *(const float4*)(zyp + d);
    sX[d+0][r]=xv.x; sX[d+1][r]=xv.y; sX[d+2][r]=xv.z; sX[d+3][r]=xv.w;
    sY[d+0][r]=yv.x; sY[d+1][r]=yv.y; sY[d+2][r]=yv.z; sY[d+3][r]=yv.w;
  }
}

__device__ __forceinline__ void compute_sv(
    const float (*sX)[TILE], const float (*sY)[TILE],
    int i0, int j0, float sv[4][4])
{
  float acc[4][4] = {{0.f}};
#pragma unroll 8
  for (int d = 0; d < DDIM; ++d) {
    float4 xv = *(const float4*)&sX[d][i0];
    float4 yv = *(const float4*)&sY[d][j0];
    float xr[4] = {xv.x, xv.y, xv.z, xv.w};
    float yc[4] = {yv.x, yv.y, yv.z, yv.w};
#pragma unroll
    for (int a = 0; a < 4; ++a)
#pragma unroll
      for (int b = 0; b < 4; ++b)
        acc[a][b] += fabsf(xr[a] - yc[b]);
  }
#pragma unroll
  for (int a = 0; a < 4; ++a)
#pragma unroll
    for (int b = 0; b < 4; ++b)
      sv[a][b] = -acc[a][b];
}

__device__ __forceinline__ void tile_stats(
    const float sv[4][4], int bi, int bj,
    float* __restrict__ rm_part, float* __restrict__ rs_part,
    float* __restrict__ cm_part, float* __restrict__ cs_part,
    float (*cmw)[TILE], float (*csw)[TILE])
{
  int t = threadIdx.x;
  int lid = t & 63, wv = t >> 6;
  int i0 = (t >> 4) << 2, j0 = (t & 15) << 2;

  float rm[4], es[4];
#pragma unroll
  for (int a = 0; a < 4; ++a)
    rm[a] = fmaxf(fmaxf(sv[a][0], sv[a][1]), fmaxf(sv[a][2], sv[a][3]));
#pragma unroll
  for (int off = 1; off <= 8; off <<= 1)
#pragma unroll
    for (int a = 0; a < 4; ++a)
      rm[a] = fmaxf(rm[a], __shfl_xor(rm[a], off));
#pragma unroll
  for (int a = 0; a < 4; ++a)
    es[a] = __expf(sv[a][0]-rm[a]) + __expf(sv[a][1]-rm[a])
          + __expf(sv[a][2]-rm[a]) + __expf(sv[a][3]-rm[a]);
#pragma unroll
  for (int off = 1; off <= 8; off <<= 1)
#pragma unroll
    for (int a = 0; a < 4; ++a)
      es[a] += __shfl_xor(es[a], off);
  if ((lid & 15) == 0) {
#pragma unroll
    for (int a = 0; a < 4; ++a) {
      int idx = bj * NROWS + bi * TILE + i0 + a;
      rm_part[idx] = rm[a];
      rs_part[idx] = es[a];
    }
  }

  float cm[4], ce[4];
#pragma unroll
  for (int b = 0; b < 4; ++b)
    cm[b] = fmaxf(fmaxf(sv[0][b], sv[1][b]), fmaxf(sv[2][b], sv[3][b]));
#pragma unroll
  for (int off = 16; off <= 32; off <<= 1)
#pragma unroll
    for (int b = 0; b < 4; ++b)
      cm[b] = fmaxf(cm[b], __shfl_xor(cm[b], off));
#pragma unroll
  for (int b = 0; b < 4; ++b)
    ce[b] = __expf(sv[0][b]-cm[b]) + __expf(sv[1][b]-cm[b])
          + __expf(sv[2][b]-cm[b]) + __expf(sv[3][b]-cm[b]);
#pragma unroll
  for (int off = 16; off <= 32; off <<= 1)
#pragma unroll
    for (int b = 0; b < 4; ++b)
      ce[b] += __shfl_xor(ce[b], off);
  if (lid < 16) {
#pragma unroll
    for (int b = 0; b < 4; ++b) {
      cmw[wv][lid * 4 + b] = cm[b];
      csw[wv][lid * 4 + b] = ce[b];
    }
  }
  __syncthreads();
  if (t < TILE) {
    int j = t;
    float M = fmaxf(fmaxf(cmw[0][j], cmw[1][j]), fmaxf(cmw[2][j], cmw[3][j]));
    float S = __expf(cmw[0][j]-M)*csw[0][j] + __expf(cmw[1][j]-M)*csw[1][j]
            + __expf(cmw[2][j]-M)*csw[2][j] + __expf(cmw[3][j]-M)*csw[3][j];
    int idx = bi * MCOLS + bj * TILE + j;
    cm_part[idx] = M;
    cs_part[idx] = S;
  }
}

// ============================================================================
// Single cooperative kernel with a hand-rolled grid barrier + ticket finish.
// barmem (u32): cnt[g] at [g*16] (16 line-spaced counters), cnt2 at [256],
// release at [272], ticket at [288]. All zeroed by host memset each call.
// ============================================================================
__global__ __launch_bounds__(256, 4) void fused_bar(
    const float* __restrict__ zx, const float* __restrict__ zy,
    float* __restrict__ rm_part, float* __restrict__ rs_part,
    float* __restrict__ cm_part, float* __restrict__ cs_part,
    float* __restrict__ part, unsigned* __restrict__ barmem,
    float* __restrict__ out)
{
  __shared__ float sX[DDIM][TILE];
  __shared__ float sY[DDIM][TILE];
  __shared__ float cmw[4][TILE];
  __shared__ float csw[4][TILE];
  __shared__ float l_rmax[TILE], l_rinv[TILE];
  __shared__ float l_cmax[2][TILE], l_cinv[2][TILE];
  __shared__ float red[8];
  __shared__ int winner;

  const int bid = blockIdx.x;
  const int t   = threadIdx.x;
  const int lid = t & 63, wv = t >> 6;
  const int i0  = (t >> 4) << 2;
  const int j0  = (t & 15) << 2;
  const int bi  = bid >> 4;          // shared by both tiles of this block
  const int bj0 = (bid << 1) & 31;   // u=0 tile-col; u=1 is bj0+1

  float sv[2][4][4];

  // ================= Phase A: distances + tile stats (2 tiles) ==============
#pragma unroll
  for (int u = 0; u < 2; ++u) {
    int bj = bj0 + u;
    stage_tiles(zx, zy, bi, bj, sX, sY);
    __syncthreads();
    compute_sv(sX, sY, i0, j0, sv[u]);
    tile_stats(sv[u], bi, bj, rm_part, rs_part, cm_part, cs_part, cmw, csw);
    __syncthreads();  // protect LDS before next iteration reuse
  }

  // ================= Grid barrier (two-level, hand-rolled) ==================
  __syncthreads();
  if (t == 0) {
    unsigned old = __hip_atomic_fetch_add(&barmem[(bid & 15) * 16], 1u,
                                          __ATOMIC_ACQ_REL, __HIP_MEMORY_SCOPE_AGENT);
    if (old == (NBLK / 16) - 1) {
      unsigned o2 = __hip_atomic_fetch_add(&barmem[256], 1u,
                                           __ATOMIC_ACQ_REL, __HIP_MEMORY_SCOPE_AGENT);
      if (o2 == 15)
        __hip_atomic_store(&barmem[272], 1u, __ATOMIC_RELEASE, __HIP_MEMORY_SCOPE_AGENT);
    }
    while (__hip_atomic_load(&barmem[272], __ATOMIC_ACQUIRE,
                             __HIP_MEMORY_SCOPE_AGENT) == 0)
      __builtin_amdgcn_s_sleep(8);
  }
  __syncthreads();

  // ====== Phase B' (redundant per-block): row/col stats from partials =======
  // threads 0..63: rows of bi; 64..191: cols of tiles u=0,1; rest idle.
  if (t < 64) {
    int i = bi * TILE + t;
    float M = -3.4e38f;
#pragma unroll 8
    for (int tj = 0; tj < NTJ; ++tj) M = fmaxf(M, rm_part[tj * NROWS + i]);
    float S = 0.f;
#pragma unroll 8
    for (int tj = 0; tj < NTJ; ++tj)
      S += __expf(rm_part[tj * NROWS + i] - M) * rs_part[tj * NROWS + i];
    l_rmax[t] = M;
    l_rinv[t] = 1.f / S;
  } else if (t < 192) {
    int u = (t - 64) >> 6, c = (t - 64) & 63;
    int j = (bj0 + u) * TILE + c;
    float M = -3.4e38f;
#pragma unroll 8
    for (int ti = 0; ti < NTI; ++ti) M = fmaxf(M, cm_part[ti * MCOLS + j]);
    float S = 0.f;
#pragma unroll 8
    for (int ti = 0; ti < NTI; ++ti)
      S += __expf(cm_part[ti * MCOLS + j] - M) * cs_part[ti * MCOLS + j];
    l_cmax[u][c] = M;
    l_cinv[u][c] = 1.f / S;
  }
  __syncthreads();

  // ============ Phase C: combine straight from registers (sv live) ==========
  {
    float pn = 0.f, pd = 0.f;
    float rm[4], rv[4];
#pragma unroll
    for (int a = 0; a < 4; ++a) {
      rm[a] = l_rmax[i0 + a];
      rv[a] = l_rinv[i0 + a];
    }
#pragma unroll
    for (int u = 0; u < 2; ++u) {
      float cm[4], cv[4];
#pragma unroll
      for (int b = 0; b < 4; ++b) {
        cm[b] = l_cmax[u][j0 + b];
        cv[b] = l_cinv[u][j0 + b];
      }
#pragma unroll
      for (int a = 0; a < 4; ++a)
#pragma unroll
        for (int b = 0; b < 4; ++b) {
          float av = __expf(sv[u][a][b] - rm[a]) * rv[a];
          float bv = __expf(sv[u][a][b] - cm[b]) * cv[b];
          float w  = av + bv - av * bv;
          pn += w * sv[u][a][b];
          pd += w;
        }
    }
#pragma unroll
    for (int off = 1; off <= 32; off <<= 1) {
      pn += __shfl_xor(pn, off);
      pd += __shfl_xor(pd, off);
    }
    if (lid == 0) { red[wv * 2] = pn; red[wv * 2 + 1] = pd; }
    __syncthreads();
    if (t == 0) {
      part[bid * 2 + 0] = red[0] + red[2] + red[4] + red[6];
      part[bid * 2 + 1] = red[1] + red[3] + red[5] + red[7];
      // ticket: last block to arrive does the final reduce
      unsigned o = __hip_atomic_fetch_add(&barmem[288], 1u,
                                          __ATOMIC_ACQ_REL, __HIP_MEMORY_SCOPE_AGENT);
      winner = (o == NBLK - 1);
    }
    __syncthreads();
  }

  // ================= Final: winner block reduces 512 partials ===============
  if (winner) {
    float pn = 0.f, pd = 0.f;
#pragma unroll
    for (int k = t; k < NBLK; k += 256) {
      pn += part[k * 2 + 0];
      pd += part[k * 2 + 1];
    }
#pragma unroll
    for (int off = 1; off <= 32; off <<= 1) {
      pn += __shfl_xor(pn, off);
      pd += __shfl_xor(pd, off);
    }
    if (lid == 0) { red[wv * 2] = pn; red[wv * 2 + 1] = pd; }
    __syncthreads();
    if (t == 0) {
      float n = red[0] + red[2] + red[4] + red[6];
      float d = red[1] + red[3] + red[5] + red[7];
      out[0] = n / d;
    }
  }
}

// ============================================================================
// Fallback path: the R2 4-kernel pipeline (known good, 46.7 us)
// ============================================================================
__device__ __forceinline__ void load_tile_s(
    const float* __restrict__ s_in, int bi, int bj, float sv[4][4])
{
  int t = threadIdx.x;
  int i0 = (t >> 4) << 2;
  int j0 = (t & 15) << 2;
  const float* base = s_in + (size_t)(bi * TILE + i0) * MCOLS + bj * TILE + j0;
#pragma unroll
  for (int a = 0; a < 4; ++a) {
    float4 v = *(const float4*)(base + (size_t)a * MCOLS);
    sv[a][0] = v.x; sv[a][1] = v.y; sv[a][2] = v.z; sv[a][3] = v.w;
  }
}

template<bool STORE>
__global__ __launch_bounds__(256) void k1_stats(
    const float* __restrict__ zx, const float* __restrict__ zy,
    float* __restrict__ s_out,
    float* __restrict__ rm_part, float* __restrict__ rs_part,
    float* __restrict__ cm_part, float* __restrict__ cs_part)
{
  __shared__ float sX[DDIM][TILE];
  __shared__ float sY[DDIM][TILE];
  __shared__ float cmw[4][TILE];
  __shared__ float csw[4][TILE];
  int bi = blockIdx.y, bj = blockIdx.x;
  int t  = threadIdx.x;
  int i0 = (t >> 4) << 2, j0 = (t & 15) << 2;
  float sv[4][4];
  stage_tiles(zx, zy, bi, bj, sX, sY);
  __syncthreads();
  compute_sv(sX, sY, i0, j0, sv);
  if (STORE) {
#pragma unroll
    for (int a = 0; a < 4; ++a) {
      float4 v = make_float4(sv[a][0], sv[a][1], sv[a][2], sv[a][3]);
      *(float4*)(s_out + (size_t)(bi * TILE + i0 + a) * MCOLS + bj * TILE + j0) = v;
    }
  }
  tile_stats(sv, bi, bj, rm_part, rs_part, cm_part, cs_part, cmw, csw);
}

__global__ __launch_bounds__(256) void kr_reduce(
    const float* __restrict__ rm_part, const float* __restrict__ rs_part,
    const float* __restrict__ cm_part, const float* __restrict__ cs_part,
    float* __restrict__ rowmax, float* __restrict__ rowinv,
    float* __restrict__ colmax, float* __restrict__ colinv)
{
  int g = blockIdx.x * 256 + threadIdx.x;
  if (g < NROWS) {
    int i = g;
    float M = -3.4e38f;
#pragma unroll 8
    for (int tj = 0; tj < NTJ; ++tj) M = fmaxf(M, rm_part[tj * NROWS + i]);
    float S = 0.f;
#pragma unroll 8
    for (int tj = 0; tj < NTJ; ++tj)
      S += __expf(rm_part[tj * NROWS + i] - M) * rs_part[tj * NROWS + i];
    rowmax[i] = M;
    rowinv[i] = 1.f / S;
  } else if (g < NROWS + MCOLS) {
    int j = g - NROWS;
    float M = -3.4e38f;
#pragma unroll 8
    for (int ti = 0; ti < NTI; ++ti) M = fmaxf(M, cm_part[ti * MCOLS + j]);
    float S = 0.f;
#pragma unroll 8
    for (int ti = 0; ti < NTI; ++ti)
      S += __expf(cm_part[ti * MCOLS + j] - M) * cs_part[ti * MCOLS + j];
    colmax[j] = M;
    colinv[j] = 1.f / S;
  }
}

template<bool STORE>
__global__ __launch_bounds__(256) void k3_final(
    const float* __restrict__ zx, const float* __restrict__ zy,
    const float* __restrict__ s_in,
    const float* __restrict__ rowmax, const float* __restrict__ rowinv,
    const float* __restrict__ colmax, const float* __restrict__ colinv,
    float* __restrict__ part)
{
  int bi = blockIdx.y, bj = blockIdx.x;
  int t  = threadIdx.x;
  int i0 = (t >> 4) << 2, j0 = (t & 15) << 2;
  float sv[4][4];
  if constexpr (STORE) {
    load_tile_s(s_in, bi, bj, sv);
  } else {
    __shared__ float sX[DDIM][TILE];
    __shared__ float sY[DDIM][TILE];
    stage_tiles(zx, zy, bi, bj, sX, sY);
    __syncthreads();
    compute_sv(sX, sY, i0, j0, sv);
  }
  float rm[4], rv[4], cm[4], cv[4];
#pragma unroll
  for (int a = 0; a < 4; ++a) {
    rm[a] = rowmax[bi * TILE + i0 + a];
    rv[a] = rowinv[bi * TILE + i0 + a];
  }
#pragma unroll
  for (int b = 0; b < 4; ++b) {
    cm[b] = colmax[bj * TILE + j0 + b];
    cv[b] = colinv[bj * TILE + j0 + b];
  }
  float pn = 0.f, pd = 0.f;
#pragma unroll
  for (int a = 0; a < 4; ++a)
#pragma unroll
    for (int b = 0; b < 4; ++b) {
      float av = __expf(sv[a][b] - rm[a]) * rv[a];
      float bv = __expf(sv[a][b] - cm[b]) * cv[b];
      float w  = av + bv - av * bv;
      pn += w * sv[a][b];
      pd += w;
    }
#pragma unroll
  for (int off = 1; off <= 32; off <<= 1) {
    pn += __shfl_xor(pn, off);
    pd += __shfl_xor(pd, off);
  }
  if ((t & 63) == 0) {
    int w = (bi * NTJ + bj) * 4 + (t >> 6);
    part[w * 2 + 0] = pn;
    part[w * 2 + 1] = pd;
  }
}

__global__ __launch_bounds__(256) void k4_out(
    const float* __restrict__ part, int n, float* __restrict__ out)
{
  int t = threadIdx.x;
  float pn = 0.f, pd = 0.f;
  for (int k = t; k < n; k += 256) {
    pn += part[k * 2 + 0];
    pd += part[k * 2 + 1];
  }
#pragma unroll
  for (int off = 1; off <= 32; off <<= 1) {
    pn += __shfl_xor(pn, off);
    pd += __shfl_xor(pd, off);
  }
  __shared__ float red[8];
  if ((t & 63) == 0) { red[(t >> 6) * 2] = pn; red[(t >> 6) * 2 + 1] = pd; }
  __syncthreads();
  if (t == 0) {
    float n2 = red[0] + red[2] + red[4] + red[6];
    float d2 = red[1] + red[3] + red[5] + red[7];
    out[0] = n2 / d2;
  }
}

extern "C" void kernel_launch(void* const* d_in, const int* in_sizes, int n_in,
                              void* d_out, int out_size, void* d_ws, size_t ws_size,
                              hipStream_t stream)
{
  const float* zx = (const float*)d_in[0];
  const float* zy = (const float*)d_in[1];
  float* out = (float*)d_out;

  char* ws = (char*)d_ws;
  unsigned* barmem = (unsigned*)(ws);           // 4 KB barrier/ticket state
  float* part    = (float*)(ws + (8  << 10));   // 512*2 (coop) / 4096*2 (fb)
  float* rowmax  = (float*)(ws + (40 << 10));   // fallback-only finals
  float* rowinv  = (float*)(ws + (48 << 10));
  float* colmax  = (float*)(ws + (56 << 10));
  float* colinv  = (float*)(ws + (64 << 10));
  float* rm_part = (float*)(ws + (128 << 10));  // 32*2048 f32 = 256 KB each
  float* rs_part = (float*)(ws + (384 << 10));
  float* cm_part = (float*)(ws + (640 << 10));
  float* cs_part = (float*)(ws + (896 << 10));
  float* s_buf   = (float*)(ws + (1152 << 10)); // 16 MiB (fallback only)

  // zero the barrier/ticket state (first replay would otherwise see 0xAA)
  hipMemsetAsync(barmem, 0, 4096, stream);

  void* args[] = {
    (void*)&zx, (void*)&zy,
    (void*)&rm_part, (void*)&rs_part, (void*)&cm_part, (void*)&cs_part,
    (void*)&part, (void*)&barmem, (void*)&out
  };
  hipError_t err = hipLaunchCooperativeKernel(
      (void*)fused_bar, dim3(NBLK), dim3(256), args, 0, stream);

  if (err != hipSuccess) {
    // ---- fallback: known-good 4-kernel pipeline ----
    dim3 grid(NTJ, NTI), block(256);
    const size_t NEED = (size_t)(1152 << 10) + (size_t)NROWS * MCOLS * sizeof(float);
    if (ws_size >= NEED) {
      k1_stats<true ><<<grid, block, 0, stream>>>(zx, zy, s_buf, rm_part, rs_part, cm_part, cs_part);
      kr_reduce<<<dim3(16), block, 0, stream>>>(rm_part, rs_part, cm_part, cs_part,
                                                rowmax, rowinv, colmax, colinv);
      k3_final<true ><<<grid, block, 0, stream>>>(zx, zy, s_buf, rowmax, rowinv, colmax, colinv, part);
    } else {
      k1_stats<false><<<grid, block, 0, stream>>>(zx, zy, s_buf, rm_part, rs_part, cm_part, cs_part);
      kr_reduce<<<dim3(16), block, 0, stream>>>(rm_part, rs_part, cm_part, cs_part,
                                                rowmax, rowinv, colmax, colinv);
      k3_final<false><<<grid, block, 0, stream>>>(zx, zy, s_buf, rowmax, rowinv, colmax, colinv, part);
    }
    k4_out<<<dim3(1), block, 0, stream>>>(part, NTI * NTJ * 4, out);
  }
}

// Round 6
// 35.715 us; speedup vs baseline: 5.0399x; 2.8400x over previous
//
#include <hip/hip_runtime.h>

#define NROWS 2048
#define MCOLS 2048
#define DDIM  64
#define TILE  64
#define NTI   32   // tile-rows
#define NTJ   32   // tile-cols

// ============================================================================
// Helpers
// ============================================================================
__device__ __forceinline__ void stage_tiles(
    const float* __restrict__ zx, const float* __restrict__ zy,
    int bi, int bj, float (*sX)[TILE], float (*sY)[TILE])
{
  int t = threadIdx.x;
  int r  = t & 63;
  int d0 = (t >> 6) << 2;
  const float* zxp = zx + (size_t)(bi * TILE + r) * DDIM;
  const float* zyp = zy + (size_t)(bj * TILE + r) * DDIM;
#pragma unroll
  for (int q = 0; q < 4; ++q) {
    int d = d0 + 16 * q;
    float4 xv = *(const float4*)(zxp + d);
    float4 yv = *(const float4*)(zyp + d);
    sX[d+0][r]=xv.x; sX[d+1][r]=xv.y; sX[d+2][r]=xv.z; sX[d+3][r]=xv.w;
    sY[d+0][r]=yv.x; sY[d+1][r]=yv.y; sY[d+2][r]=yv.z; sY[d+3][r]=yv.w;
  }
}

__device__ __forceinline__ void compute_sv(
    const float (*sX)[TILE], const float (*sY)[TILE],
    int i0, int j0, float sv[4][4])
{
  float acc[4][4] = {{0.f}};
#pragma unroll 8
  for (int d = 0; d < DDIM; ++d) {
    float4 xv = *(const float4*)&sX[d][i0];
    float4 yv = *(const float4*)&sY[d][j0];
    float xr[4] = {xv.x, xv.y, xv.z, xv.w};
    float yc[4] = {yv.x, yv.y, yv.z, yv.w};
#pragma unroll
    for (int a = 0; a < 4; ++a)
#pragma unroll
      for (int b = 0; b < 4; ++b)
        acc[a][b] += fabsf(xr[a] - yc[b]);
  }
#pragma unroll
  for (int a = 0; a < 4; ++a)
#pragma unroll
    for (int b = 0; b < 4; ++b)
      sv[a][b] = -acc[a][b];
}

// ============================================================================
// K1: distances -> store s + per-tile (max, expsum) partials for rows & cols.
//   rm_part/rs_part: [NTJ][NROWS]   cm_part/cs_part: [NTI][MCOLS]
// ============================================================================
__global__ __launch_bounds__(256) void k1_dist(
    const float* __restrict__ zx, const float* __restrict__ zy,
    float* __restrict__ s_out,
    float* __restrict__ rm_part, float* __restrict__ rs_part,
    float* __restrict__ cm_part, float* __restrict__ cs_part)
{
  __shared__ float sX[DDIM][TILE];
  __shared__ float sY[DDIM][TILE];
  __shared__ float cmw[4][TILE];
  __shared__ float csw[4][TILE];

  int bi = blockIdx.y, bj = blockIdx.x;
  int t  = threadIdx.x;
  int lid = t & 63, wv = t >> 6;
  int i0 = (t >> 4) << 2, j0 = (t & 15) << 2;

  stage_tiles(zx, zy, bi, bj, sX, sY);
  __syncthreads();
  float sv[4][4];
  compute_sv(sX, sY, i0, j0, sv);

#pragma unroll
  for (int a = 0; a < 4; ++a) {
    float4 v = make_float4(sv[a][0], sv[a][1], sv[a][2], sv[a][3]);
    *(float4*)(s_out + (size_t)(bi * TILE + i0 + a) * MCOLS + bj * TILE + j0) = v;
  }

  // ---- row stats: 16 lanes (bits 0..3) cover one tile-row ----
  float rm[4], es[4];
#pragma unroll
  for (int a = 0; a < 4; ++a)
    rm[a] = fmaxf(fmaxf(sv[a][0], sv[a][1]), fmaxf(sv[a][2], sv[a][3]));
#pragma unroll
  for (int off = 1; off <= 8; off <<= 1)
#pragma unroll
    for (int a = 0; a < 4; ++a)
      rm[a] = fmaxf(rm[a], __shfl_xor(rm[a], off));
#pragma unroll
  for (int a = 0; a < 4; ++a)
    es[a] = __expf(sv[a][0]-rm[a]) + __expf(sv[a][1]-rm[a])
          + __expf(sv[a][2]-rm[a]) + __expf(sv[a][3]-rm[a]);
#pragma unroll
  for (int off = 1; off <= 8; off <<= 1)
#pragma unroll
    for (int a = 0; a < 4; ++a)
      es[a] += __shfl_xor(es[a], off);
  if ((lid & 15) == 0) {
#pragma unroll
    for (int a = 0; a < 4; ++a) {
      int idx = bj * NROWS + bi * TILE + i0 + a;
      rm_part[idx] = rm[a];
      rs_part[idx] = es[a];
    }
  }

  // ---- col stats: bits 4..5 within wave, then LDS across 4 waves ----
  float cm[4], ce[4];
#pragma unroll
  for (int b = 0; b < 4; ++b)
    cm[b] = fmaxf(fmaxf(sv[0][b], sv[1][b]), fmaxf(sv[2][b], sv[3][b]));
#pragma unroll
  for (int off = 16; off <= 32; off <<= 1)
#pragma unroll
    for (int b = 0; b < 4; ++b)
      cm[b] = fmaxf(cm[b], __shfl_xor(cm[b], off));
#pragma unroll
  for (int b = 0; b < 4; ++b)
    ce[b] = __expf(sv[0][b]-cm[b]) + __expf(sv[1][b]-cm[b])
          + __expf(sv[2][b]-cm[b]) + __expf(sv[3][b]-cm[b]);
#pragma unroll
  for (int off = 16; off <= 32; off <<= 1)
#pragma unroll
    for (int b = 0; b < 4; ++b)
      ce[b] += __shfl_xor(ce[b], off);
  if (lid < 16) {
#pragma unroll
    for (int b = 0; b < 4; ++b) {
      cmw[wv][lid * 4 + b] = cm[b];
      csw[wv][lid * 4 + b] = ce[b];
    }
  }
  __syncthreads();
  if (t < TILE) {
    int j = t;
    float M = fmaxf(fmaxf(cmw[0][j], cmw[1][j]), fmaxf(cmw[2][j], cmw[3][j]));
    float S = __expf(cmw[0][j]-M)*csw[0][j] + __expf(cmw[1][j]-M)*csw[1][j]
            + __expf(cmw[2][j]-M)*csw[2][j] + __expf(cmw[3][j]-M)*csw[3][j];
    int idx = bi * MCOLS + bj * TILE + j;
    cm_part[idx] = M;
    cs_part[idx] = S;
  }
}

// ============================================================================
// K2: per-block redundant stats-reduce (from L2/L3-hot partials) + reload s
//     tile + combine -> one (pn,pd) pair per block. No atomics.
// ============================================================================
__global__ __launch_bounds__(256) void k2_combine(
    const float* __restrict__ s_in,
    const float* __restrict__ rm_part, const float* __restrict__ rs_part,
    const float* __restrict__ cm_part, const float* __restrict__ cs_part,
    float* __restrict__ part /* [NTI*NTJ][2] */)
{
  __shared__ float l_rmax[TILE], l_rinv[TILE];
  __shared__ float l_cmax[TILE], l_cinv[TILE];
  __shared__ float red[8];

  int bi = blockIdx.y, bj = blockIdx.x;
  int t  = threadIdx.x;
  int lid = t & 63, wv = t >> 6;
  int i0 = (t >> 4) << 2, j0 = (t & 15) << 2;

  // ---- redundant reduce of 32 partials for the 64 rows + 64 cols we need ---
  if (t < 64) {
    int i = bi * TILE + t;
    float m[NTJ];
#pragma unroll
    for (int tj = 0; tj < NTJ; ++tj) m[tj] = rm_part[tj * NROWS + i];
    float M = m[0];
#pragma unroll
    for (int tj = 1; tj < NTJ; ++tj) M = fmaxf(M, m[tj]);
    float S = 0.f;
#pragma unroll
    for (int tj = 0; tj < NTJ; ++tj)
      S += __expf(m[tj] - M) * rs_part[tj * NROWS + i];
    l_rmax[t] = M;
    l_rinv[t] = 1.f / S;
  } else if (t < 128) {
    int c = t - 64;
    int j = bj * TILE + c;
    float m[NTI];
#pragma unroll
    for (int ti = 0; ti < NTI; ++ti) m[ti] = cm_part[ti * MCOLS + j];
    float M = m[0];
#pragma unroll
    for (int ti = 1; ti < NTI; ++ti) M = fmaxf(M, m[ti]);
    float S = 0.f;
#pragma unroll
    for (int ti = 0; ti < NTI; ++ti)
      S += __expf(m[ti] - M) * cs_part[ti * MCOLS + j];
    l_cmax[c] = M;
    l_cinv[c] = 1.f / S;
  }
  __syncthreads();

  // ---- reload s tile and combine ----
  float sv[4][4];
  {
    const float* base = s_in + (size_t)(bi * TILE + i0) * MCOLS + bj * TILE + j0;
#pragma unroll
    for (int a = 0; a < 4; ++a) {
      float4 v = *(const float4*)(base + (size_t)a * MCOLS);
      sv[a][0] = v.x; sv[a][1] = v.y; sv[a][2] = v.z; sv[a][3] = v.w;
    }
  }
  float rm[4], rv[4], cm[4], cv[4];
#pragma unroll
  for (int a = 0; a < 4; ++a) {
    rm[a] = l_rmax[i0 + a];
    rv[a] = l_rinv[i0 + a];
  }
#pragma unroll
  for (int b = 0; b < 4; ++b) {
    cm[b] = l_cmax[j0 + b];
    cv[b] = l_cinv[j0 + b];
  }
  float pn = 0.f, pd = 0.f;
#pragma unroll
  for (int a = 0; a < 4; ++a)
#pragma unroll
    for (int b = 0; b < 4; ++b) {
      float av = __expf(sv[a][b] - rm[a]) * rv[a];
      float bv = __expf(sv[a][b] - cm[b]) * cv[b];
      float w  = av + bv - av * bv;
      pn += w * sv[a][b];
      pd += w;
    }
#pragma unroll
  for (int off = 1; off <= 32; off <<= 1) {
    pn += __shfl_xor(pn, off);
    pd += __shfl_xor(pd, off);
  }
  if (lid == 0) { red[wv * 2] = pn; red[wv * 2 + 1] = pd; }
  __syncthreads();
  if (t == 0) {
    int bid = bi * NTJ + bj;
    part[bid * 2 + 0] = red[0] + red[2] + red[4] + red[6];
    part[bid * 2 + 1] = red[1] + red[3] + red[5] + red[7];
  }
}

// ============================================================================
// K3: deterministic reduce of 1024 (pn,pd) pairs -> out scalar.
// ============================================================================
__global__ __launch_bounds__(256) void k3_out(
    const float* __restrict__ part, float* __restrict__ out)
{
  int t = threadIdx.x;
  float pn = 0.f, pd = 0.f;
#pragma unroll
  for (int k = t; k < NTI * NTJ; k += 256) {
    float2 v = *(const float2*)(part + k * 2);
    pn += v.x;
    pd += v.y;
  }
#pragma unroll
  for (int off = 1; off <= 32; off <<= 1) {
    pn += __shfl_xor(pn, off);
    pd += __shfl_xor(pd, off);
  }
  __shared__ float red[8];
  if ((t & 63) == 0) { red[(t >> 6) * 2] = pn; red[(t >> 6) * 2 + 1] = pd; }
  __syncthreads();
  if (t == 0) {
    float n = red[0] + red[2] + red[4] + red[6];
    float d = red[1] + red[3] + red[5] + red[7];
    out[0] = n / d;
  }
}

extern "C" void kernel_launch(void* const* d_in, const int* in_sizes, int n_in,
                              void* d_out, int out_size, void* d_ws, size_t ws_size,
                              hipStream_t stream)
{
  const float* zx = (const float*)d_in[0];
  const float* zy = (const float*)d_in[1];
  float* out = (float*)d_out;

  char* ws = (char*)d_ws;
  float* part    = (float*)(ws + 0);            // 1024*2 f32 = 8 KB
  float* rm_part = (float*)(ws + (64  << 10));  // 32*2048 f32 = 256 KB each
  float* rs_part = (float*)(ws + (320 << 10));
  float* cm_part = (float*)(ws + (576 << 10));
  float* cs_part = (float*)(ws + (832 << 10));
  float* s_buf   = (float*)(ws + (1088 << 10)); // 16 MiB

  dim3 grid(NTJ, NTI), block(256);
  k1_dist   <<<grid, block, 0, stream>>>(zx, zy, s_buf,
                                         rm_part, rs_part, cm_part, cs_part);
  k2_combine<<<grid, block, 0, stream>>>(s_buf,
                                         rm_part, rs_part, cm_part, cs_part, part);
  k3_out    <<<dim3(1), block, 0, stream>>>(part, out);
}